// Round 12
// baseline (262.320 us; speedup 1.0000x reference)
//
#include <hip/hip_runtime.h>
#include <math.h>

#define T_LEN 32000
#define B_N 8
#define O_N 128
#define NTAPS 10
#define NTHREADS 256
#define UT 8                          // consecutive t per lane
#define TILE_T (NTHREADS * UT)        // 2048
#define PAD 2944                      // >= 9*Dmax = 2880; PAD % 8 == 0
#define NSTAGE (TILE_T + PAD + 1)     // 4993 logical dwords
// skewed layout: chunk of 8 dwords -> 9 slots; slot 9c+8 duplicates x[8c+8]
#define SL(d) (9 * ((d) >> 3) + ((d) & 7))
#define NSLOTS 5620                   // > SL(4992)=5616; 22.0 KB -> 7 blocks/CU
#define OCHUNK 8
#define TC 1024                       // tile-center offset (const-frac quantization)

// ---------------- kernel 1: per-channel tap parameters -> d_ws ----------------
__global__ __launch_bounds__(128) void comb_params_kernel(
    const float* __restrict__ f, const float* __restrict__ a,
    float* __restrict__ tp) {
  int o = threadIdx.x;  // 128 threads, 1 block
  double fr = (double)f[o];
  double sig = 1.0 / (1.0 + exp(-fr));
  float ff = (float)(50.0 * pow(40.0, sig));
  float D = 16000.0f / ff;
  float av = a[o];
  for (int k = 0; k < NTAPS; ++k) {
    tp[o * 20 + k] = (float)k * D;
    tp[o * 20 + 10 + k] = (float)pow((double)av, (double)k);
  }
}

#define LOAD_PARAMS                                                        \
  const float4* p4 = (const float4*)(tp + (oc + oi) * 20);                 \
  float4 v0 = p4[0], v1 = p4[1], v2 = p4[2], v3 = p4[3], v4 = p4[4];       \
  float kD[NTAPS] = {v0.x, v0.y, v0.z, v0.w, v1.x,                         \
                     v1.y, v1.z, v1.w, v2.x, v2.y};                        \
  float ak[NTAPS] = {v2.z, v2.w, v3.x, v3.y, v3.z,                         \
                     v3.w, v4.x, v4.y, v4.z, v4.w};

// ---------------- fast body (bx >= 2: all taps valid, const-frac) ------------
// Window of 9 dwords per (k, lane) from the dup-skewed LDS: 4 ds_read2_b32 +
// 1 ds_read_b32. Lane slot stride = 9 (gcd(9,32)=1 -> uniform banks, the
// conflict-free class measured ~0 in R6/R7). Pair bases sb+2r+cr, cr=(s+2r>=8);
// the chunk-pad duplicate makes every pair consecutive-slot (incl. s+2r==7
// crossings, where slot 9c+8 duplicates dword 8(c+1)).
// R10 bug fixed: Sk subtracts t0 (window base is tile-relative).
__device__ __forceinline__ void comb_body_fast(const float* __restrict__ tp,
                                               float* __restrict__ outp,
                                               const float* sxd, int oc,
                                               int t0, int tid, bool do_store) {
  float tcf = (float)(t0 + TC);
  int nt9 = 9 * tid;
  // k=0 identity tap: x[t..t+7]; S0 = PAD (mod 8 == 0) -> fully static
  int sb0 = 9 * (PAD >> 3) + nt9;
  float z0 = sxd[sb0],     z1 = sxd[sb0 + 1], z2 = sxd[sb0 + 2],
        z3 = sxd[sb0 + 3], z4 = sxd[sb0 + 4], z5 = sxd[sb0 + 5],
        z6 = sxd[sb0 + 6], z7 = sxd[sb0 + 7];
#pragma unroll 1
  for (int oi = 0; oi < OCHUNK; ++oi) {
    LOAD_PARAMS
    float acc[UT] = {z0, z1, z2, z3, z4, z5, z6, z7};  // a^0 * x[t]
#pragma unroll
    for (int k = 1; k < NTAPS; ++k) {
      float pc = tcf - kD[k];                  // reference pos at t_c (>0 here)
      float fc = __builtin_amdgcn_fractf(pc);  // frac_ref(t_c), exact
      int Sk = (int)(pc - fc) + (PAD - TC - t0);  // tile-relative; in [64,2943]
      int s = Sk & 7;
      int sb = 9 * (Sk >> 3) + s + nt9;        // slot of window dword 0
      float wB = ak[k] * fc;
      float wA = ak[k] - wB;
      // pair r: offsets (2r+cr, 2r+1+cr), cr=(s+2r>=8); r=0 -> cr=0 static
      int c1 = (s >= 6), c2 = (s >= 4), c3 = (s >= 2);
      float q0 = sxd[sb],          q1 = sxd[sb + 1];
      float q2 = sxd[sb + 2 + c1], q3 = sxd[sb + 3 + c1];
      float q4 = sxd[sb + 4 + c2], q5 = sxd[sb + 5 + c2];
      float q6 = sxd[sb + 6 + c3], q7 = sxd[sb + 7 + c3];
      float q8 = sxd[sb + 9];
      acc[0] = fmaf(wA, q0, fmaf(wB, q1, acc[0]));
      acc[1] = fmaf(wA, q1, fmaf(wB, q2, acc[1]));
      acc[2] = fmaf(wA, q2, fmaf(wB, q3, acc[2]));
      acc[3] = fmaf(wA, q3, fmaf(wB, q4, acc[3]));
      acc[4] = fmaf(wA, q4, fmaf(wB, q5, acc[4]));
      acc[5] = fmaf(wA, q5, fmaf(wB, q6, acc[5]));
      acc[6] = fmaf(wA, q6, fmaf(wB, q7, acc[6]));
      acc[7] = fmaf(wA, q7, fmaf(wB, q8, acc[7]));
    }
    if (do_store) {
      float4* o4 = (float4*)(outp + (size_t)oi * T_LEN);  // 16B-aligned
      o4[0] = make_float4(acc[0], acc[1], acc[2], acc[3]);
      o4[1] = make_float4(acc[4], acc[5], acc[6], acc[7]);
    }
  }
}

// ---------------- exact body (edge tiles bx 0..1: per-t arithmetic + mask) ---
__device__ __forceinline__ void comb_body_edge(const float* __restrict__ tp,
                                               float* __restrict__ outp,
                                               const float* sxd, int oc,
                                               int t0, int tid, int base_g) {
  float tf[UT];
#pragma unroll
  for (int u = 0; u < UT; ++u) tf[u] = (float)(t0 + UT * tid + u);
#pragma unroll 1
  for (int oi = 0; oi < OCHUNK; ++oi) {
    LOAD_PARAMS
    float acc[UT];
#pragma unroll
    for (int u = 0; u < UT; ++u) acc[u] = 0.0f;
#pragma unroll
    for (int k = 0; k < NTAPS; ++k) {
#pragma unroll
      for (int u = 0; u < UT; ++u) {
        float pos = tf[u] - kD[k];                  // fl(t - kD), exact chain
        float frac = __builtin_amdgcn_fractf(pos);
        int idx = (int)pos - base_g;                // trunc==floor for pos>=0
        float x0 = sxd[SL(idx)];                    // neg-pos taps masked below
        float x1 = sxd[SL(idx + 1)];
        float tap = fmaf(frac, x1 - x0, x0);
        tap = (pos >= 0.0f) ? tap : 0.0f;           // valid = (floor(pos)>=0)
        acc[u] = fmaf(ak[k], tap, acc[u]);
      }
    }
    float4* o4 = (float4*)(outp + (size_t)oi * T_LEN);
    o4[0] = make_float4(acc[0], acc[1], acc[2], acc[3]);
    o4[1] = make_float4(acc[4], acc[5], acc[6], acc[7]);
  }
}

__global__ __launch_bounds__(256) void comb_main_kernel(
    const float* __restrict__ x, const float* __restrict__ tp,
    float* __restrict__ out) {
  __shared__ float sxd[NSLOTS];
  int bx = blockIdx.x;
  int t0 = bx * TILE_T;
  int b = blockIdx.y;
  int oc = blockIdx.z * OCHUNK;
  const float* __restrict__ xrow = x + b * T_LEN;
  int base_g = t0 - PAD;
  int tid = threadIdx.x;

  // Stage logical dwords [0, NSTAGE) into skewed slots; chunk pads get the
  // duplicate of the next chunk's first element (written when p%8==0, p>=8).
  if (bx >= 2 && bx <= 14) {
    // interior: base_g >= 0 and base_g + 4992 <= 30720 -> no clamps
#pragma unroll 1
    for (int p = tid; p < NSTAGE; p += 256) {
      float v = xrow[base_g + p];
      int jj = SL(p);
      sxd[jj] = v;
      if ((p & 7) == 0 && p >= 8) sxd[jj - 1] = v;  // dup into prev pad
    }
  } else {
    // bx 0,1: g<0 -> 0.0 (masked taps read finite zeros)
    // bx 15:  g can exceed 31999 -> clamp to T-1 (reference i1 clip, weight 0)
#pragma unroll 1
    for (int p = tid; p < NSTAGE; p += 256) {
      int g = base_g + p;
      float v = 0.0f;
      if (g >= 0) v = xrow[g < T_LEN - 1 ? g : T_LEN - 1];
      int jj = SL(p);
      sxd[jj] = v;
      if ((p & 7) == 0 && p >= 8) sxd[jj - 1] = v;
    }
  }
  __syncthreads();

  float* outp = out + ((size_t)b * O_N + oc) * T_LEN + t0 + UT * tid;

  if (bx >= 2) {
    // all taps valid (t >= 4096 > 2880 = 9*Dmax); bx==15: 32000-30720=1280
    // outputs = 160 lanes x 8 -> lanes tid<160 store, others compute+discard
    comb_body_fast(tp, outp, sxd, oc, t0, tid, bx < 15 || tid < 160);
  } else {
    comb_body_edge(tp, outp, sxd, oc, t0, tid, base_g);
  }
}

// ---------------- launch ----------------
extern "C" void kernel_launch(void* const* d_in, const int* in_sizes, int n_in,
                              void* d_out, int out_size, void* d_ws,
                              size_t ws_size, hipStream_t stream) {
  const float* x = (const float*)d_in[0];  // (8,1,32000) f32
  const float* f = (const float*)d_in[1];  // (128,1) f32
  const float* a = (const float*)d_in[2];  // (128,1) f32
  float* out = (float*)d_out;              // (8,128,32000) f32
  float* tp = (float*)d_ws;                // 128*20 floats = 10 KB scratch

  comb_params_kernel<<<1, 128, 0, stream>>>(f, a, tp);

  dim3 grid(16, B_N, O_N / OCHUNK);  // (16, 8, 16) = 2048 blocks
  comb_main_kernel<<<grid, 256, 0, stream>>>(x, tp, out);
}